// Round 5
// baseline (950.196 us; speedup 1.0000x reference)
//
#include <hip/hip_runtime.h>
#include <hip/hip_bf16.h>

#define BB 256
#define DD 512
#define LL 32
#define HWN 196
#define TT 8
#define STEPB 12544   // bytes per packed K-step chunk: 196 n-cells * 8 kq * 8B

typedef __hip_bfloat16 bf16;
typedef __attribute__((ext_vector_type(8))) short short8;
typedef __attribute__((ext_vector_type(4))) float f32x4;

__device__ __forceinline__ float b2f(bf16 x) { return __bfloat162float(x); }
__device__ __forceinline__ unsigned short f2bu(float x) {
    bf16 h = __float2bfloat16(x);
    return *(unsigned short*)&h;
}
__device__ __forceinline__ float bu2f(unsigned short u) {
    bf16 h = *(bf16*)&u;
    return __bfloat162float(h);
}
#define NEG_INF (-__builtin_huge_valf())

// ---- async global->LDS (wave-uniform LDS base + lane*size; global addr per-lane) ----
__device__ __forceinline__ void gload_lds16(const void* g, void* l) {
    __builtin_amdgcn_global_load_lds(
        (const __attribute__((address_space(1))) void*)g,
        (__attribute__((address_space(3))) void*)l, 16, 0, 0);
}
__device__ __forceinline__ void gload_lds4(const void* g, void* l) {
    __builtin_amdgcn_global_load_lds(
        (const __attribute__((address_space(1))) void*)g,
        (__attribute__((address_space(3))) void*)l, 4, 0, 0);
}

// ---------------- f32 -> bf16 weight convert: all three weights, one launch ----------------
__global__ __launch_bounds__(256) void cvt3_kernel(
    const float* __restrict__ s0, unsigned short* __restrict__ d0,     // 65536 x4
    const float* __restrict__ s1, unsigned short* __restrict__ d1,     // 131072 x4
    const float* __restrict__ s2, unsigned short* __restrict__ d2)     // 65536 x4
{
    int blk = blockIdx.x, tid = threadIdx.x;
    const float* s; unsigned short* d; int i;
    if (blk < 256)      { s = s0; d = d0; i = blk*256 + tid; }
    else if (blk < 768) { s = s1; d = d1; i = (blk-256)*256 + tid; }
    else                { s = s2; d = d2; i = (blk-768)*256 + tid; }
    float4 f = ((const float4*)s)[i];
    ushort4 u;
    u.x = f2bu(f.x); u.y = f2bu(f.y); u.z = f2bu(f.z); u.w = f2bu(f.w);
    ((ushort4*)d)[i] = u;
}

// ---------------- pack f32 X[b][c][hw] -> MFMA-B-ready packed chunks ----------------
// Chunk layout ([n][kq]): byte n*64 + kq*8; cell(n,kq) = uint2{c0|c1<<16, c2|c3<<16},
// cj = X[s*32 + kq*4 + j][n]. A lane's B-frag (k = lq*8..+7 at col n) is the 16
// contiguous bytes at n*64 + lq*16 -> single ds_read_b128.
__global__ __launch_bounds__(256) void pack_x_kernel(
    const float* __restrict__ X, char* __restrict__ Xp)
{
    int b = blockIdx.x, s = blockIdx.y;
    char* chunk = Xp + ((size_t)(b*16 + s))*STEPB;
    for (int i = threadIdx.x; i < 4*HWN; i += 256) {
        int n = i >> 2, kqp = i & 3;          // kq pair: kq = 2*kqp, 2*kqp+1
        const float* base = X + ((size_t)b*DD + s*32 + kqp*8)*HWN + n;
        uint v[4];
        #pragma unroll
        for (int h = 0; h < 4; ++h) {
            float f0 = base[(size_t)(2*h+0)*HWN], f1 = base[(size_t)(2*h+1)*HWN];
            v[h] = (uint)f2bu(f0) | ((uint)f2bu(f1) << 16);
        }
        *(uint4*)(chunk + n*64 + kqp*16) = make_uint4(v[0], v[1], v[2], v[3]);
    }
}

// ---------------- small GEMM: out[b,d] = sum_k X[b,k]*W[d,k] + bias[d] ----------------
// grid (BB, Dout/256): blockIdx.y picks a 256-wide d-chunk -> one output/thread,
// 2-4x more blocks than before (was 1 block/CU, latency-bound).
__global__ __launch_bounds__(256) void small_gemm_kernel(
    const float* __restrict__ A1, int K1,
    const float* __restrict__ A2, int K2,
    const float* __restrict__ Wt, const float* __restrict__ bias,
    float* __restrict__ outf, int Dout)
{
    __shared__ float xs[1024];
    int b = blockIdx.x, tid = threadIdx.x;
    int K = K1 + K2;
    for (int i = tid; i < K; i += 256) {
        xs[i] = (i < K1) ? A1[(size_t)b*K1 + i] : A2[(size_t)b*K2 + (i - K1)];
    }
    __syncthreads();
    int d = blockIdx.y*256 + tid;
    const float4* wrow = (const float4*)(Wt + (size_t)d * K);
    float acc = 0.f;
    for (int j = 0; j < K/4; ++j) {
        float4 w = wrow[j];
        acc += w.x*xs[j*4] + w.y*xs[j*4+1] + w.z*xs[j*4+2] + w.w*xs[j*4+3];
    }
    if (bias) acc += bias[d];
    outf[(size_t)b*Dout + d] = acc;
}

// ---------------- ControlUnit attention ----------------
__global__ __launch_bounds__(256) void control_kernel(
    const float* __restrict__ cq, const float* __restrict__ cw,
    const float* __restrict__ Wca, const float* __restrict__ bca,
    const int* __restrict__ mask,
    float* __restrict__ cnew_f, float* __restrict__ cv_out, float* __restrict__ cnew_out)
{
    __shared__ float u[DD];
    __shared__ float cas[LL];
    __shared__ float cvs[LL];
    int b = blockIdx.x, tid = threadIdx.x;
    for (int d = tid; d < DD; d += 256) u[d] = cq[(size_t)b*DD + d] * Wca[d];
    __syncthreads();
    int wave = tid >> 6, lane = tid & 63;
    float bca0 = bca[0];
    for (int lw = 0; lw < 8; ++lw) {
        int l = wave*8 + lw;
        const float4* w4 = (const float4*)(cw + ((size_t)(b*LL + l))*DD + lane*8);
        float4 wa = w4[0], wb = w4[1];
        const float* uu = &u[lane*8];
        float p = wa.x*uu[0] + wa.y*uu[1] + wa.z*uu[2] + wa.w*uu[3]
                + wb.x*uu[4] + wb.y*uu[5] + wb.z*uu[6] + wb.w*uu[7];
        for (int off = 32; off > 0; off >>= 1) p += __shfl_down(p, off);
        if (lane == 0) {
            float v = p + bca0;
            if (mask[b*LL + l] <= 0) v = NEG_INF;
            cas[l] = v;
        }
    }
    __syncthreads();
    if (tid < LL) {
        float mx = NEG_INF;
        for (int j = 0; j < LL; ++j) mx = fmaxf(mx, cas[j]);
        float s = 0.f;
        for (int j = 0; j < LL; ++j) s += __expf(cas[j] - mx);
        float cv = __expf(cas[tid] - mx) / s;
        cvs[tid] = cv;
        cv_out[b*LL + tid] = cv;
    }
    __syncthreads();
    for (int d = tid; d < DD; d += 256) {
        float acc = 0.f;
        for (int l = 0; l < LL; ++l) acc += cvs[l] * cw[((size_t)(b*LL + l))*DD + d];
        cnew_f[(size_t)b*DD + d] = acc;
        cnew_out[(size_t)b*DD + d] = acc;
    }
}

// ---------------- MFMA conv1x1 batched GEMM, 3-deep DMA pipeline ----------------
// Round-5 change: 2wm x 4wn wave mapping, 4 m-tiles/wave. Per wave per K-step:
// 3-4 ds_read_b128 (was 13) feeding 12-16 MFMA (was 26 from 13 reads) — the LDS
// read pipe was ~3x oversubscribed vs the matrix pipe with the old 2-mt mapping.
// acc 4x4xf32x4 = 64 VGPR; launch_bounds(512,4) caps at 128 VGPR -> 2 blocks/CU.
// Counted-vmcnt pipeline (T4) unchanged from round 4.
__global__ __launch_bounds__(512, 4) void conv_mfma_kernel(
    const char* __restrict__ X1p, int ns1,
    const char* __restrict__ X2p, int ns2,
    const unsigned short* __restrict__ Wb, int C,
    const float* __restrict__ bias, const float* __restrict__ oscale,
    void* __restrict__ Yout, int packed_out)
{
    // 13312 = max read extent (tile 12: n up to 207 -> 207*64+64); bytes past 12544 are
    // never-staged pad whose values are discarded by the hw<196 store guard.
    __shared__ __align__(16) char Xs[4][13312];
    int b = blockIdx.x, ot = blockIdx.y;
    int tid = threadIdx.x;
    int wave = tid >> 6, lane = tid & 63;
    int wm = wave >> 2, wn = wave & 3;
    int obase = ot*128 + wm*64;
    int t0 = wn*3;                    // n-tiles [t0, t0+ntn): wn0..2 -> 3 tiles, wn3 -> 4
    int ntn = (wn == 3) ? 4 : 3;
    int ln = lane & 15, lq = lane >> 4;
    int nsteps = ns1 + ns2;

    auto STAGE = [&](int s) {
        const char* chunk = (s < ns1) ? X1p + ((size_t)b*ns1 + s)*STEPB
                                      : X2p + ((size_t)b*ns2 + (s - ns1))*STEPB;
        char* lb = Xs[s & 3];
        // 13 ops: waves 0-4 issue 2x 1KB; waves 5,6 1x 1KB; wave 7: 1KB + 256B tail
        gload_lds16(chunk + wave*1024 + lane*16, lb + wave*1024);
        if (wave < 5)       gload_lds16(chunk + (wave+8)*1024 + lane*16, lb + (wave+8)*1024);
        else if (wave == 7) gload_lds4 (chunk + 12288 + lane*4, lb + 12288);
    };
    auto ALOAD = [&](int s, short8* a) {
        #pragma unroll
        for (int mt = 0; mt < 4; ++mt)
            a[mt] = *(const short8*)(Wb + (size_t)(obase + mt*16 + ln)*C + s*32 + lq*8);
    };

    f32x4 acc[4][4];
    #pragma unroll
    for (int mt = 0; mt < 4; ++mt)
        #pragma unroll
        for (int nt = 0; nt < 4; ++nt) acc[mt][nt] = (f32x4){0.f, 0.f, 0.f, 0.f};

    short8 a_cur[4], a_nxt[4];

    // prologue: FIFO = [X0, X1, A0, X2]
    STAGE(0);
    STAGE(1);
    __builtin_amdgcn_sched_barrier(0);
    ALOAD(0, a_cur);
    __builtin_amdgcn_sched_barrier(0);
    STAGE(2);

    auto BODY = [&](int s, bool doA, bool doX) {
        __builtin_amdgcn_s_barrier();
        if (doA) ALOAD(s + 1, a_nxt);
        __builtin_amdgcn_sched_barrier(0);
        if (doX) STAGE(s + 3);
        __builtin_amdgcn_sched_barrier(0);
        const char* curb = Xs[s & 3];
        #pragma unroll
        for (int nt = 0; nt < 4; ++nt) {
            if (nt < ntn) {
                int n = (t0 + nt)*16 + ln;
                union { uint4 u; short8 s8; } bb;
                bb.u = *(const uint4*)(curb + n*64 + lq*16);
                #pragma unroll
                for (int mt = 0; mt < 4; ++mt)
                    acc[mt][nt] = __builtin_amdgcn_mfma_f32_16x16x32_bf16(a_cur[mt], bb.s8, acc[mt][nt], 0, 0, 0);
            }
        }
        #pragma unroll
        for (int mt = 0; mt < 4; ++mt) a_cur[mt] = a_nxt[mt];
    };

    for (int s = 0; s <= nsteps - 4; ++s) {
        asm volatile("s_waitcnt vmcnt(2)" ::: "memory");
        __builtin_amdgcn_sched_barrier(0);
        BODY(s, true, true);
    }
    {   // s = nsteps-3: STAGE(nsteps-1) already in flight
        asm volatile("s_waitcnt vmcnt(2)" ::: "memory");
        __builtin_amdgcn_sched_barrier(0);
        BODY(nsteps - 3, true, false);
    }
    {   // s = nsteps-2
        asm volatile("s_waitcnt vmcnt(0)" ::: "memory");
        __builtin_amdgcn_sched_barrier(0);
        BODY(nsteps - 2, true, false);
    }
    {   // s = nsteps-1
        asm volatile("s_waitcnt vmcnt(0)" ::: "memory");
        __builtin_amdgcn_sched_barrier(0);
        BODY(nsteps - 1, false, false);
    }

    // ---- epilogue: C/D layout col = lane&15, row = (lane>>4)*4 + reg ----
    if (packed_out) {
        uint2* Yp = (uint2*)Yout;
        #pragma unroll
        for (int mt = 0; mt < 4; ++mt) {
            int o4 = obase + mt*16 + lq*4;
            int st = o4 >> 5, kqo = (o4 & 31) >> 2;
            uint2* chunk = Yp + (size_t)(b*16 + st)*1568;   // 1568 uint2 = STEPB
            float bo[4], os[4];
            #pragma unroll
            for (int rr = 0; rr < 4; ++rr) {
                bo[rr] = bias[o4 + rr];
                os[rr] = oscale ? oscale[(size_t)b*DD + o4 + rr] : 1.f;
            }
            #pragma unroll
            for (int nt = 0; nt < 4; ++nt) {
                int hw = (t0 + nt)*16 + ln;
                if (nt < ntn && hw < HWN) {
                    unsigned short v[4];
                    #pragma unroll
                    for (int rr = 0; rr < 4; ++rr)
                        v[rr] = f2bu((acc[mt][nt][rr] + bo[rr]) * os[rr]);
                    chunk[hw*8 + kqo] =
                        make_uint2((uint)v[0] | ((uint)v[1] << 16),
                                   (uint)v[2] | ((uint)v[3] << 16));
                }
            }
        }
    } else {
        unsigned short* Y = (unsigned short*)Yout;
        #pragma unroll
        for (int mt = 0; mt < 4; ++mt) {
            #pragma unroll
            for (int rr = 0; rr < 4; ++rr) {
                int o = obase + mt*16 + lq*4 + rr;
                float bo = bias[o];
                float os = oscale ? oscale[(size_t)b*DD + o] : 1.f;
                #pragma unroll
                for (int nt = 0; nt < 4; ++nt) {
                    int hw = (t0 + nt)*16 + ln;
                    if (nt < ntn && hw < HWN) {
                        float v = (acc[mt][nt][rr] + bo) * os;
                        Y[((size_t)b*DD + o)*HWN + hw] = f2bu(v);
                    }
                }
            }
        }
    }
}

// ---------------- softmax S1: partial per-hw max / sum-exp over a 64-c slice ----------------
// grid (BB, 4); thread (half, hw): slice sl = y*2+half covers c [sl*64, sl*64+64).
// chain length 64 (was 256). Stored (pm bf16, ps f32) are self-consistent: ps is
// rebased onto the bf16-rounded pm, so S2's combine is exact.
__global__ __launch_bounds__(512) void softmax_part_kernel(
    const bf16* __restrict__ ra,
    unsigned short* __restrict__ pm_part, float* __restrict__ ps_part,
    float* __restrict__ r_zero)
{
    int b = blockIdx.x, y = blockIdx.y, tid = threadIdx.x;
    if (y == 0) r_zero[(size_t)b*DD + tid] = 0.f;   // zero r for S2's atomics
    int half = tid >> 8, hw = tid & 255;
    if (hw < HWN) {
        int sl = y*2 + half;
        const bf16* base = ra + ((size_t)b*DD + sl*64)*HWN + hw;
        float m = NEG_INF, s = 0.f;
        for (int c = 0; c < 64; ++c) {
            float x = b2f(base[(size_t)c*HWN]);
            float nm = fmaxf(m, x);
            s = s*__expf(m - nm) + __expf(x - nm);
            m = nm;
        }
        unsigned short pmu = f2bu(m);
        float pmf = bu2f(pmu);
        s *= __expf(m - pmf);                       // rebase onto rounded max
        size_t idx = ((size_t)sl*BB + b)*HWN + hw;
        pm_part[idx] = pmu;
        ps_part[idx] = s;
    }
}

// ---------------- softmax S2: combine partials; rv = exp(ra-mx)/s; r += rv*k ----------------
// grid (BB, 2): hw-halves of 98. r accumulated with 2 commutative atomicAdds
// (deterministic: f32 add is commutative; r zeroed in S1).
__global__ __launch_bounds__(512) void softmax_rv_kernel(
    const bf16* __restrict__ ra, const float* __restrict__ kin,
    const unsigned short* __restrict__ pm_part, const float* __restrict__ ps_part,
    float* __restrict__ rv, float* __restrict__ r)
{
    __shared__ float mxs[98], sis[98];
    int b = blockIdx.x, h = blockIdx.y, tid = threadIdx.x;
    int hwb = h*98;
    if (tid < 98) {
        int hw = hwb + tid;
        float pmv[8], mx = NEG_INF;
        #pragma unroll
        for (int i = 0; i < 8; ++i) {
            pmv[i] = bu2f(pm_part[((size_t)i*BB + b)*HWN + hw]);
            mx = fmaxf(mx, pmv[i]);
        }
        float s = 0.f;
        #pragma unroll
        for (int i = 0; i < 8; ++i)
            s += ps_part[((size_t)i*BB + b)*HWN + hw] * __expf(pmv[i] - mx);
        mxs[tid] = mx; sis[tid] = 1.f/s;
    }
    __syncthreads();
    int wave = tid >> 6, lane = tid & 63;
    for (int ci = 0; ci < 64; ++ci) {
        int c = wave*64 + ci;
        size_t rowbase = ((size_t)b*DD + c)*HWN + hwb;
        float psum = 0.f;
        #pragma unroll
        for (int g = 0; g < 2; ++g) {
            int j = g*64 + lane;
            if (j < 98) {
                float e = __expf(b2f(ra[rowbase + j]) - mxs[j]) * sis[j];
                rv[rowbase + j] = e;
                psum += e * kin[rowbase + j];
            }
        }
        for (int off = 32; off > 0; off >>= 1) psum += __shfl_down(psum, off);
        if (lane == 0) atomicAdd(&r[(size_t)b*DD + c], psum);
    }
}

// ---------------- sa softmax over T and m_sa (gate fused in) ----------------
__global__ __launch_bounds__(256) void samsa_kernel(
    const float* __restrict__ cs, const float* __restrict__ ms,
    const float* __restrict__ Wsa, const float* __restrict__ bsa,
    const float* __restrict__ cnew, const float* __restrict__ Wc, const float* __restrict__ bc,
    float* __restrict__ gate_out, float* __restrict__ msa)
{
    __shared__ float lg[TT];
    __shared__ float sas[TT];
    __shared__ float xw[DD];
    __shared__ float gsh;
    int b = blockIdx.x, tid = threadIdx.x;
    int wave = tid >> 6, lane = tid & 63;
    for (int d = tid; d < DD; d += 256) xw[d] = Wsa[d];
    __syncthreads();
    for (int tw = 0; tw < 2; ++tw) {
        int t = wave + 4*tw;
        const float4* c4 = (const float4*)(cs + ((size_t)t*BB + b)*DD + lane*8);
        float4 ca = c4[0], cb = c4[1];
        const float* ww = &xw[lane*8];
        float p = ca.x*ww[0] + ca.y*ww[1] + ca.z*ww[2] + ca.w*ww[3]
                + cb.x*ww[4] + cb.y*ww[5] + cb.z*ww[6] + cb.w*ww[7];
        for (int off = 32; off > 0; off >>= 1) p += __shfl_down(p, off);
        if (lane == 0) lg[t] = p;           // raw dot; gate applied after
    }
    if (wave == 0) {
        const float4* w4 = (const float4*)(Wc + lane*8);
        const float* x = &cnew[(size_t)b*DD + lane*8];
        float4 wa = w4[0], wb = w4[1];
        float p = wa.x*x[0] + wa.y*x[1] + wa.z*x[2] + wa.w*x[3]
                + wb.x*x[4] + wb.y*x[5] + wb.z*x[6] + wb.w*x[7];
        for (int off = 32; off > 0; off >>= 1) p += __shfl_down(p, off);
        if (lane == 0) {
            float g = 1.f / (1.f + __expf(-(p + bc[0])));
            gsh = g; gate_out[b] = g;
        }
    }
    __syncthreads();
    if (tid < TT) {
        float g = gsh, b0 = bsa[0];
        float mx = NEG_INF;
        for (int j = 0; j < TT; ++j) mx = fmaxf(mx, g*lg[j] + b0);
        float s = 0.f;
        for (int j = 0; j < TT; ++j) s += __expf(g*lg[j] + b0 - mx);
        sas[tid] = __expf(g*lg[tid] + b0 - mx) / s;
    }
    __syncthreads();
    for (int d = tid; d < DD; d += 256) {
        float acc = 0.f;
        for (int t = 0; t < TT; ++t) acc += sas[t] * ms[((size_t)t*BB + b)*DD + d];
        msa[(size_t)b*DD + d] = acc;
    }
}

// ---------------- m_new = g*m + (1-g)*(mund + msa@Ws^T)  (GEMM + final fused) ----------------
__global__ __launch_bounds__(256) void write_final_kernel(
    const float* __restrict__ msa, const float* __restrict__ Ws,
    const float* __restrict__ m, const float* __restrict__ gate,
    const float* __restrict__ mund, float* __restrict__ mnew)
{
    __shared__ float xs[DD];
    int b = blockIdx.x, tid = threadIdx.x;
    for (int i = tid; i < DD; i += 256) xs[i] = msa[(size_t)b*DD + i];
    __syncthreads();
    float g = gate[b];
    int d = blockIdx.y*256 + tid;
    const float4* wrow = (const float4*)(Ws + (size_t)d * DD);
    float acc = 0.f;
    for (int j = 0; j < DD/4; ++j) {
        float4 w = wrow[j];
        acc += w.x*xs[j*4] + w.y*xs[j*4+1] + w.z*xs[j*4+2] + w.w*xs[j*4+3];
    }
    size_t idx = (size_t)b*DD + d;
    mnew[idx] = g * m[idx] + (1.f - g) * (mund[idx] + acc);
}

extern "C" void kernel_launch(void* const* d_in, const int* in_sizes, int n_in,
                              void* d_out, int out_size, void* d_ws, size_t ws_size,
                              hipStream_t stream)
{
    (void)in_sizes; (void)n_in; (void)out_size; (void)ws_size;
    const float* c    = (const float*)d_in[0];
    const float* m    = (const float*)d_in[1];
    const float* k    = (const float*)d_in[2];
    const float* q    = (const float*)d_in[3];
    const float* cw   = (const float*)d_in[4];
    const int*   mask = (const int*)  d_in[5];
    const float* cs   = (const float*)d_in[6];
    const float* ms   = (const float*)d_in[7];
    const float* Wcq  = (const float*)d_in[8];
    const float* bcq  = (const float*)d_in[9];
    const float* Wca  = (const float*)d_in[10];
    const float* bca  = (const float*)d_in[11];
    const float* Wm_r = (const float*)d_in[12];
    const float* bm_r = (const float*)d_in[13];
    const float* Wk   = (const float*)d_in[14];
    const float* bk   = (const float*)d_in[15];
    const float* WI   = (const float*)d_in[16];
    const float* bI   = (const float*)d_in[17];
    const float* Wra  = (const float*)d_in[18];
    const float* bra  = (const float*)d_in[19];
    const float* Wm_w = (const float*)d_in[20];
    const float* bm_w = (const float*)d_in[21];
    const float* Wsa  = (const float*)d_in[22];
    const float* bsa  = (const float*)d_in[23];
    const float* Wm2  = (const float*)d_in[24];
    const float* bm2  = (const float*)d_in[25];
    const float* Wc   = (const float*)d_in[26];
    const float* bc   = (const float*)d_in[27];
    const float* Ws   = (const float*)d_in[28];

    float* out_cnew = (float*)d_out;
    float* out_mnew = out_cnew + BB*DD;
    float* out_cv   = out_mnew + BB*DD;
    float* out_rv   = out_cv + BB*LL;     // 25,690,112 f32 = 102,760,448 B

    // d_out rv region doubles as packed bf16 scratch for Ip / I2p (dead before rv write)
    char* Ip  = (char*)out_rv;                       // 256*16*12544 = 51,380,224 B
    char* I2p = (char*)out_rv + 51380224;            // 51,380,224 B

    char* w = (char*)d_ws;                 // total footprint: 55,575,552 B (unchanged)
    float* s0      = (float*)(w + 0);        // cq -> r (r zeroed by S1, atomics in S2)
    float* s1      = (float*)(w + 524288);   // cnew (alive until samsa)
    // pm_part overlays s2+s3 head (mI dead after conv1; mprev/msa written after S2)
    unsigned short* pm_part = (unsigned short*)(w + 1048576);  // 8*256*196*2 = 802,816 B
    // ps_part overlays the weight region (Wkb/WIb/Wrab dead after conv3)
    float* ps_part = (float*)(w + 2097152);                    // 8*256*196*4 = 1,605,632 B
    unsigned short* Wkb  = (unsigned short*)(w + 2097152);   // 512x512 bf16
    unsigned short* WIb  = (unsigned short*)(w + 2621440);   // 512x1024 bf16
    unsigned short* Wrab = (unsigned short*)(w + 3670016);   // 512x512 bf16
    char* kp_ra = (char*)(w + 4194304);      // kp (packed k); ra overwrites after conv2
    float* gate_w  = (float*)(w + 55574528); // 1024 B

    float* cq_w   = s0;
    float* r_w    = s0;
    float* cnew_w = s1;
    float* mI_w   = (float*)(w + 1048576);   // s2 region (dead before pm_part is written)
    float* mund_w = (float*)(w + 1048576);
    float* mprev_w= (float*)(w + 1572864);   // s3 region
    float* msa_w  = (float*)(w + 1572864);
    unsigned short* ra_w = (unsigned short*)kp_ra;   // conv3 output, [b][c][hw] bf16

    // Weight converts (f32 -> bf16), one launch
    cvt3_kernel<<<1024, 256, 0, stream>>>(Wk, Wkb, WI, WIb, Wra, Wrab);

    // Pack k once into MFMA-B layout (f32 103MB -> packed bf16 51MB)
    pack_x_kernel<<<dim3(BB, 16), 256, 0, stream>>>(k, kp_ra);

    // ControlUnit
    small_gemm_kernel<<<dim3(BB,2), 256, 0, stream>>>(c, DD, q, DD, Wcq, bcq, cq_w, DD);
    small_gemm_kernel<<<dim3(BB,2), 256, 0, stream>>>(m, DD, nullptr, 0, Wm_r, bm_r, mI_w, DD);
    control_kernel<<<BB, 256, 0, stream>>>(cq_w, cw, Wca, bca, mask, cnew_w, out_cv, out_cnew);

    // ReadUnit (MFMA convs): I = mI.(Wk k + bk); I2' = (WI [I;k] + bI).cnew; ra = Wra I2' + bra
    conv_mfma_kernel<<<dim3(BB, 4), 512, 0, stream>>>(kp_ra, 16, nullptr, 0,  Wkb,  DD,   bk,  mI_w,   Ip,   1);
    conv_mfma_kernel<<<dim3(BB, 4), 512, 0, stream>>>(Ip,    16, kp_ra,  16,  WIb,  2*DD, bI,  cnew_w, I2p,  1);
    conv_mfma_kernel<<<dim3(BB, 4), 512, 0, stream>>>(I2p,   16, nullptr, 0,  Wrab, DD,   bra, nullptr, ra_w, 0);

    // channel softmax + r, two-stage
    softmax_part_kernel<<<dim3(BB, 4), 512, 0, stream>>>((const bf16*)ra_w, pm_part, ps_part, r_w);
    softmax_rv_kernel<<<dim3(BB, 2), 512, 0, stream>>>((const bf16*)ra_w, k, pm_part, ps_part, out_rv, r_w);

    // WriteUnit
    small_gemm_kernel<<<dim3(BB,2), 256, 0, stream>>>(r_w, DD, m, DD, Wm_w, bm_w, mprev_w, DD);
    small_gemm_kernel<<<dim3(BB,2), 256, 0, stream>>>(mprev_w, DD, nullptr, 0, Wm2, bm2, mund_w, DD);
    samsa_kernel<<<BB, 256, 0, stream>>>(cs, ms, Wsa, bsa, cnew_w, Wc, bc, gate_w, msa_w);
    write_final_kernel<<<dim3(BB,2), 256, 0, stream>>>(msa_w, Ws, m, gate_w, mund_w, out_mnew);
}

// Round 6
// 783.522 us; speedup vs baseline: 1.2127x; 1.2127x over previous
//
#include <hip/hip_runtime.h>
#include <hip/hip_bf16.h>

#define BB 256
#define DD 512
#define LL 32
#define HWN 196
#define TT 8
#define STEPB 12544   // bytes per packed K-step chunk: 196 n-cells * 8 kq * 8B

typedef __hip_bfloat16 bf16;
typedef __attribute__((ext_vector_type(8))) short short8;
typedef __attribute__((ext_vector_type(4))) float f32x4;

__device__ __forceinline__ float b2f(bf16 x) { return __bfloat162float(x); }
__device__ __forceinline__ unsigned short f2bu(float x) {
    bf16 h = __float2bfloat16(x);
    return *(unsigned short*)&h;
}
__device__ __forceinline__ float bu2f(unsigned short u) {
    bf16 h = *(bf16*)&u;
    return __bfloat162float(h);
}
#define NEG_INF (-__builtin_huge_valf())

// ---- async global->LDS (wave-uniform LDS base + lane*16; global addr per-lane) ----
__device__ __forceinline__ void gload_lds16(const void* g, void* l) {
    __builtin_amdgcn_global_load_lds(
        (const __attribute__((address_space(1))) void*)g,
        (__attribute__((address_space(3))) void*)l, 16, 0, 0);
}

// ---------------- f32 -> bf16 weight convert: all three weights, one launch ----------------
__global__ __launch_bounds__(256) void cvt3_kernel(
    const float* __restrict__ s0, unsigned short* __restrict__ d0,     // 65536 x4
    const float* __restrict__ s1, unsigned short* __restrict__ d1,     // 131072 x4
    const float* __restrict__ s2, unsigned short* __restrict__ d2)     // 65536 x4
{
    int blk = blockIdx.x, tid = threadIdx.x;
    const float* s; unsigned short* d; int i;
    if (blk < 256)      { s = s0; d = d0; i = blk*256 + tid; }
    else if (blk < 768) { s = s1; d = d1; i = (blk-256)*256 + tid; }
    else                { s = s2; d = d2; i = (blk-768)*256 + tid; }
    float4 f = ((const float4*)s)[i];
    ushort4 u;
    u.x = f2bu(f.x); u.y = f2bu(f.y); u.z = f2bu(f.z); u.w = f2bu(f.w);
    ((ushort4*)d)[i] = u;
}

// ---------------- pack f32 X[b][c][hw] -> MFMA-B-ready packed chunks ----------------
// Chunk layout ([n][q], QUAD-SWIZZLED): cell (n, q=kq pair) at byte
// n*64 + (q ^ ((n>>1)&3))*16.  Unswizzled, a wave's ds_read_b128 (addr n*64+lq*16,
// n = base+ln) gives each 16-lane subgroup only 2 of 8 LDS quad-groups -> 8-way
// conflict (3.4M/dispatch measured r5). Swizzled: quad-group = (n&1)<<2 |
// (lq^((n>>1)&3)) -> bijection of n&7 per lq -> 2 lanes/bank = free (m136).
// Same mapping applied at pack-write, conv-read, conv packed-epilogue (rule #21);
// the DMA staging copy stays linear.
__global__ __launch_bounds__(256) void pack_x_kernel(
    const float* __restrict__ X, char* __restrict__ Xp)
{
    int b = blockIdx.x, s = blockIdx.y;
    char* chunk = Xp + ((size_t)(b*16 + s))*STEPB;
    for (int i = threadIdx.x; i < 4*HWN; i += 256) {
        int n = i >> 2, kqp = i & 3;          // kq pair: kq = 2*kqp, 2*kqp+1
        const float* base = X + ((size_t)b*DD + s*32 + kqp*8)*HWN + n;
        uint v[4];
        #pragma unroll
        for (int h = 0; h < 4; ++h) {
            float f0 = base[(size_t)(2*h+0)*HWN], f1 = base[(size_t)(2*h+1)*HWN];
            v[h] = (uint)f2bu(f0) | ((uint)f2bu(f1) << 16);
        }
        int q = kqp ^ ((n>>1)&3);
        *(uint4*)(chunk + n*64 + q*16) = make_uint4(v[0], v[1], v[2], v[3]);
    }
}

// ---------------- small GEMM: out[b,d] = sum_k X[b,k]*W[d,k] + bias[d] ----------------
// grid (BB, Dout/256): one output/thread, 2x blocks vs monolithic (TLP).
__global__ __launch_bounds__(256) void small_gemm_kernel(
    const float* __restrict__ A1, int K1,
    const float* __restrict__ A2, int K2,
    const float* __restrict__ Wt, const float* __restrict__ bias,
    float* __restrict__ outf, int Dout)
{
    __shared__ float xs[1024];
    int b = blockIdx.x, tid = threadIdx.x;
    int K = K1 + K2;
    for (int i = tid; i < K; i += 256) {
        xs[i] = (i < K1) ? A1[(size_t)b*K1 + i] : A2[(size_t)b*K2 + (i - K1)];
    }
    __syncthreads();
    int d = blockIdx.y*256 + tid;
    const float4* wrow = (const float4*)(Wt + (size_t)d * K);
    float acc = 0.f;
    for (int j = 0; j < K/4; ++j) {
        float4 w = wrow[j];
        acc += w.x*xs[j*4] + w.y*xs[j*4+1] + w.z*xs[j*4+2] + w.w*xs[j*4+3];
    }
    if (bias) acc += bias[d];
    outf[(size_t)b*Dout + d] = acc;
}

// ---------------- ControlUnit attention ----------------
__global__ __launch_bounds__(256) void control_kernel(
    const float* __restrict__ cq, const float* __restrict__ cw,
    const float* __restrict__ Wca, const float* __restrict__ bca,
    const int* __restrict__ mask,
    float* __restrict__ cnew_f, float* __restrict__ cv_out, float* __restrict__ cnew_out)
{
    __shared__ float u[DD];
    __shared__ float cas[LL];
    __shared__ float cvs[LL];
    int b = blockIdx.x, tid = threadIdx.x;
    for (int d = tid; d < DD; d += 256) u[d] = cq[(size_t)b*DD + d] * Wca[d];
    __syncthreads();
    int wave = tid >> 6, lane = tid & 63;
    float bca0 = bca[0];
    for (int lw = 0; lw < 8; ++lw) {
        int l = wave*8 + lw;
        const float4* w4 = (const float4*)(cw + ((size_t)(b*LL + l))*DD + lane*8);
        float4 wa = w4[0], wb = w4[1];
        const float* uu = &u[lane*8];
        float p = wa.x*uu[0] + wa.y*uu[1] + wa.z*uu[2] + wa.w*uu[3]
                + wb.x*uu[4] + wb.y*uu[5] + wb.z*uu[6] + wb.w*uu[7];
        for (int off = 32; off > 0; off >>= 1) p += __shfl_down(p, off);
        if (lane == 0) {
            float v = p + bca0;
            if (mask[b*LL + l] <= 0) v = NEG_INF;
            cas[l] = v;
        }
    }
    __syncthreads();
    if (tid < LL) {
        float mx = NEG_INF;
        for (int j = 0; j < LL; ++j) mx = fmaxf(mx, cas[j]);
        float s = 0.f;
        for (int j = 0; j < LL; ++j) s += __expf(cas[j] - mx);
        float cv = __expf(cas[tid] - mx) / s;
        cvs[tid] = cv;
        cv_out[b*LL + tid] = cv;
    }
    __syncthreads();
    for (int d = tid; d < DD; d += 256) {
        float acc = 0.f;
        for (int l = 0; l < LL; ++l) acc += cvs[l] * cw[((size_t)(b*LL + l))*DD + d];
        cnew_f[(size_t)b*DD + d] = acc;
        cnew_out[(size_t)b*DD + d] = acc;
    }
}

// ---------------- MFMA conv1x1 batched GEMM, DMA pipeline (round-4 structure) ----------------
// REVERTED to the proven round-4 config after r5's 4-mt rebalance collapsed the
// pipeline (vmcnt(2) no longer matched 6 ops/iter -> synchronous; 98->177us).
// 4wm x 2wn, 2 m-tiles x 7/6 n-tiles, acc[2][7], 2 A-loads/iter.
// NEW this round: quad-swizzled B-read (see pack_x comment) kills the 8-way
// ds_read_b128 subgroup conflict; chunk-12 OOB source clamped.
__global__ __launch_bounds__(512) void conv_mfma_kernel(
    const char* __restrict__ X1p, int ns1,
    const char* __restrict__ X2p, int ns2,
    const unsigned short* __restrict__ Wb, int C,
    const float* __restrict__ bias, const float* __restrict__ oscale,
    void* __restrict__ Yout, int packed_out)
{
    // 13312 = max read extent (wn1 nt5: n up to 207 -> 207*64+64); bytes past 12544
    // are garbage pad whose products are discarded by the hw<196 store guard.
    __shared__ __align__(16) char Xs[4][13312];
    int b = blockIdx.x, ot = blockIdx.y;
    int tid = threadIdx.x;
    int wave = tid >> 6, lane = tid & 63;
    int wm = wave >> 1, wn = wave & 1;
    int obase = ot*128 + wm*32;
    int n0 = wn*112;              // wn0: tiles 0..6 (n 0..111), wn1: tiles 0..5 (n 112..207)
    int ntn = wn ? 6 : 7;
    int ln = lane & 15, lq = lane >> 4;
    int nsteps = ns1 + ns2;

    auto STAGE = [&](int s) {
        const char* chunk = (s < ns1) ? X1p + ((size_t)b*ns1 + s)*STEPB
                                      : X2p + ((size_t)b*ns2 + (s - ns1))*STEPB;
        char* lb = Xs[s & 3];
        // 13 x 1KB ops: waves 0-4 two, waves 5-7 one. Chunk 12 is 256B real data;
        // OOB lanes clamp their (per-lane) source to chunk start -> garbage to pad LDS.
        gload_lds16(chunk + wave*1024 + lane*16, lb + wave*1024);
        if (wave < 5) {
            int off = (wave+8)*1024 + lane*16;
            const char* src = chunk + (off < STEPB ? off : 0);
            gload_lds16(src, lb + (wave+8)*1024);
        }
    };
    auto ALOAD = [&](int s, short8& a0, short8& a1) {
        a0 = *(const short8*)(Wb + (size_t)(obase + ln)*C + s*32 + lq*8);
        a1 = *(const short8*)(Wb + (size_t)(obase + 16 + ln)*C + s*32 + lq*8);
    };

    f32x4 acc[2][7];
    #pragma unroll
    for (int mt = 0; mt < 2; ++mt)
        #pragma unroll
        for (int nt = 0; nt < 7; ++nt) acc[mt][nt] = (f32x4){0.f, 0.f, 0.f, 0.f};

    short8 a0c, a1c, a0n, a1n;

    // prologue: FIFO = [X0, X1, A0, X2]
    STAGE(0);
    STAGE(1);
    __builtin_amdgcn_sched_barrier(0);
    ALOAD(0, a0c, a1c);
    __builtin_amdgcn_sched_barrier(0);
    STAGE(2);

    auto BODY = [&](int s, bool doA, bool doX) {
        __builtin_amdgcn_s_barrier();
        if (doA) ALOAD(s + 1, a0n, a1n);
        __builtin_amdgcn_sched_barrier(0);
        if (doX) STAGE(s + 3);
        __builtin_amdgcn_sched_barrier(0);
        const char* curb = Xs[s & 3];
        #pragma unroll
        for (int nt = 0; nt < 7; ++nt) {
            if (nt < ntn) {
                int n = n0 + nt*16 + ln;
                int q = lq ^ ((n>>1)&3);
                union { uint4 u; short8 s8; } bb;
                bb.u = *(const uint4*)(curb + n*64 + q*16);
                acc[0][nt] = __builtin_amdgcn_mfma_f32_16x16x32_bf16(a0c, bb.s8, acc[0][nt], 0, 0, 0);
                acc[1][nt] = __builtin_amdgcn_mfma_f32_16x16x32_bf16(a1c, bb.s8, acc[1][nt], 0, 0, 0);
            }
        }
        a0c = a0n; a1c = a1n;
    };

    for (int s = 0; s <= nsteps - 4; ++s) {
        asm volatile("s_waitcnt vmcnt(2)" ::: "memory");
        __builtin_amdgcn_sched_barrier(0);
        BODY(s, true, true);
    }
    {   // s = nsteps-3: STAGE(nsteps-1) already in flight
        asm volatile("s_waitcnt vmcnt(2)" ::: "memory");
        __builtin_amdgcn_sched_barrier(0);
        BODY(nsteps - 3, true, false);
    }
    {   // s = nsteps-2
        asm volatile("s_waitcnt vmcnt(0)" ::: "memory");
        __builtin_amdgcn_sched_barrier(0);
        BODY(nsteps - 2, true, false);
    }
    {   // s = nsteps-1
        asm volatile("s_waitcnt vmcnt(0)" ::: "memory");
        __builtin_amdgcn_sched_barrier(0);
        BODY(nsteps - 1, false, false);
    }

    // ---- epilogue: C/D layout col = lane&15, row = (lane>>4)*4 + reg ----
    if (packed_out) {
        // write Y in the (swizzled) pack layout for the next conv in the chain
        uint2* Yp = (uint2*)Yout;
        #pragma unroll
        for (int mt = 0; mt < 2; ++mt) {
            int o4 = obase + mt*16 + lq*4;          // 4 consecutive o = this lane's rr 0..3
            int st = o4 >> 5, kqo = (o4 & 31) >> 2; // kqo in 0..7 (8B units)
            int qh = kqo >> 1, rb = kqo & 1;
            uint2* chunk = Yp + (size_t)(b*16 + st)*1568;   // 1568 uint2 = STEPB
            float bo[4], os[4];
            #pragma unroll
            for (int rr = 0; rr < 4; ++rr) {
                bo[rr] = bias[o4 + rr];
                os[rr] = oscale ? oscale[(size_t)b*DD + o4 + rr] : 1.f;
            }
            #pragma unroll
            for (int nt = 0; nt < 7; ++nt) {
                int hw = n0 + nt*16 + ln;
                if (nt < ntn && hw < HWN) {
                    unsigned short v[4];
                    #pragma unroll
                    for (int rr = 0; rr < 4; ++rr)
                        v[rr] = f2bu((acc[mt][nt][rr] + bo[rr]) * os[rr]);
                    int qs = qh ^ ((hw>>1)&3);
                    chunk[hw*8 + qs*2 + rb] =
                        make_uint2((uint)v[0] | ((uint)v[1] << 16),
                                   (uint)v[2] | ((uint)v[3] << 16));
                }
            }
        }
    } else {
        unsigned short* Y = (unsigned short*)Yout;
        #pragma unroll
        for (int mt = 0; mt < 2; ++mt) {
            #pragma unroll
            for (int rr = 0; rr < 4; ++rr) {
                int o = obase + mt*16 + lq*4 + rr;
                float bo = bias[o];
                float os = oscale ? oscale[(size_t)b*DD + o] : 1.f;
                #pragma unroll
                for (int nt = 0; nt < 7; ++nt) {
                    int hw = n0 + nt*16 + ln;
                    if (nt < ntn && hw < HWN) {
                        float v = (acc[mt][nt][rr] + bo) * os;
                        Y[((size_t)b*DD + o)*HWN + hw] = f2bu(v);
                    }
                }
            }
        }
    }
}

// ---------------- softmax S1: partial per-hw max / sum-exp over a 64-c slice ----------------
// grid (BB, 4); thread (half, hw): slice sl = y*2+half covers c [sl*64, sl*64+64).
// Stored (pm bf16, ps f32) self-consistent: ps rebased onto bf16-rounded pm.
__global__ __launch_bounds__(512) void softmax_part_kernel(
    const bf16* __restrict__ ra,
    unsigned short* __restrict__ pm_part, float* __restrict__ ps_part,
    float* __restrict__ r_zero)
{
    int b = blockIdx.x, y = blockIdx.y, tid = threadIdx.x;
    if (y == 0) r_zero[(size_t)b*DD + tid] = 0.f;   // zero r for S2's atomics
    int half = tid >> 8, hw = tid & 255;
    if (hw < HWN) {
        int sl = y*2 + half;
        const bf16* base = ra + ((size_t)b*DD + sl*64)*HWN + hw;
        float m = NEG_INF, s = 0.f;
        for (int c = 0; c < 64; ++c) {
            float x = b2f(base[(size_t)c*HWN]);
            float nm = fmaxf(m, x);
            s = s*__expf(m - nm) + __expf(x - nm);
            m = nm;
        }
        unsigned short pmu = f2bu(m);
        float pmf = bu2f(pmu);
        s *= __expf(m - pmf);                       // rebase onto rounded max
        size_t idx = ((size_t)sl*BB + b)*HWN + hw;
        pm_part[idx] = pmu;
        ps_part[idx] = s;
    }
}

// ---------------- softmax S2: combine partials; rv = exp(ra-mx)/s; r += rv*k ----------------
// grid (BB, 2): hw-halves of 98. r accumulated with 2 commutative atomicAdds.
__global__ __launch_bounds__(512) void softmax_rv_kernel(
    const bf16* __restrict__ ra, const float* __restrict__ kin,
    const unsigned short* __restrict__ pm_part, const float* __restrict__ ps_part,
    float* __restrict__ rv, float* __restrict__ r)
{
    __shared__ float mxs[98], sis[98];
    int b = blockIdx.x, h = blockIdx.y, tid = threadIdx.x;
    int hwb = h*98;
    if (tid < 98) {
        int hw = hwb + tid;
        float pmv[8], mx = NEG_INF;
        #pragma unroll
        for (int i = 0; i < 8; ++i) {
            pmv[i] = bu2f(pm_part[((size_t)i*BB + b)*HWN + hw]);
            mx = fmaxf(mx, pmv[i]);
        }
        float s = 0.f;
        #pragma unroll
        for (int i = 0; i < 8; ++i)
            s += ps_part[((size_t)i*BB + b)*HWN + hw] * __expf(pmv[i] - mx);
        mxs[tid] = mx; sis[tid] = 1.f/s;
    }
    __syncthreads();
    int wave = tid >> 6, lane = tid & 63;
    for (int ci = 0; ci < 64; ++ci) {
        int c = wave*64 + ci;
        size_t rowbase = ((size_t)b*DD + c)*HWN + hwb;
        float psum = 0.f;
        #pragma unroll
        for (int g = 0; g < 2; ++g) {
            int j = g*64 + lane;
            if (j < 98) {
                float e = __expf(b2f(ra[rowbase + j]) - mxs[j]) * sis[j];
                rv[rowbase + j] = e;
                psum += e * kin[rowbase + j];
            }
        }
        for (int off = 32; off > 0; off >>= 1) psum += __shfl_down(psum, off);
        if (lane == 0) atomicAdd(&r[(size_t)b*DD + c], psum);
    }
}

// ---------------- sa softmax over T and m_sa (gate fused in) ----------------
__global__ __launch_bounds__(256) void samsa_kernel(
    const float* __restrict__ cs, const float* __restrict__ ms,
    const float* __restrict__ Wsa, const float* __restrict__ bsa,
    const float* __restrict__ cnew, const float* __restrict__ Wc, const float* __restrict__ bc,
    float* __restrict__ gate_out, float* __restrict__ msa)
{
    __shared__ float lg[TT];
    __shared__ float sas[TT];
    __shared__ float xw[DD];
    __shared__ float gsh;
    int b = blockIdx.x, tid = threadIdx.x;
    int wave = tid >> 6, lane = tid & 63;
    for (int d = tid; d < DD; d += 256) xw[d] = Wsa[d];
    __syncthreads();
    for (int tw = 0; tw < 2; ++tw) {
        int t = wave + 4*tw;
        const float4* c4 = (const float4*)(cs + ((size_t)t*BB + b)*DD + lane*8);
        float4 ca = c4[0], cb = c4[1];
        const float* ww = &xw[lane*8];
        float p = ca.x*ww[0] + ca.y*ww[1] + ca.z*ww[2] + ca.w*ww[3]
                + cb.x*ww[4] + cb.y*ww[5] + cb.z*ww[6] + cb.w*ww[7];
        for (int off = 32; off > 0; off >>= 1) p += __shfl_down(p, off);
        if (lane == 0) lg[t] = p;           // raw dot; gate applied after
    }
    if (wave == 0) {
        const float4* w4 = (const float4*)(Wc + lane*8);
        const float* x = &cnew[(size_t)b*DD + lane*8];
        float4 wa = w4[0], wb = w4[1];
        float p = wa.x*x[0] + wa.y*x[1] + wa.z*x[2] + wa.w*x[3]
                + wb.x*x[4] + wb.y*x[5] + wb.z*x[6] + wb.w*x[7];
        for (int off = 32; off > 0; off >>= 1) p += __shfl_down(p, off);
        if (lane == 0) {
            float g = 1.f / (1.f + __expf(-(p + bc[0])));
            gsh = g; gate_out[b] = g;
        }
    }
    __syncthreads();
    if (tid < TT) {
        float g = gsh, b0 = bsa[0];
        float mx = NEG_INF;
        for (int j = 0; j < TT; ++j) mx = fmaxf(mx, g*lg[j] + b0);
        float s = 0.f;
        for (int j = 0; j < TT; ++j) s += __expf(g*lg[j] + b0 - mx);
        sas[tid] = __expf(g*lg[tid] + b0 - mx) / s;
    }
    __syncthreads();
    for (int d = tid; d < DD; d += 256) {
        float acc = 0.f;
        for (int t = 0; t < TT; ++t) acc += sas[t] * ms[((size_t)t*BB + b)*DD + d];
        msa[(size_t)b*DD + d] = acc;
    }
}

// ---------------- m_new = g*m + (1-g)*(mund + msa@Ws^T)  (GEMM + final fused) ----------------
__global__ __launch_bounds__(256) void write_final_kernel(
    const float* __restrict__ msa, const float* __restrict__ Ws,
    const float* __restrict__ m, const float* __restrict__ gate,
    const float* __restrict__ mund, float* __restrict__ mnew)
{
    __shared__ float xs[DD];
    int b = blockIdx.x, tid = threadIdx.x;
    for (int i = tid; i < DD; i += 256) xs[i] = msa[(size_t)b*DD + i];
    __syncthreads();
    float g = gate[b];
    int d = blockIdx.y*256 + tid;
    const float4* wrow = (const float4*)(Ws + (size_t)d * DD);
    float acc = 0.f;
    for (int j = 0; j < DD/4; ++j) {
        float4 w = wrow[j];
        acc += w.x*xs[j*4] + w.y*xs[j*4+1] + w.z*xs[j*4+2] + w.w*xs[j*4+3];
    }
    size_t idx = (size_t)b*DD + d;
    mnew[idx] = g * m[idx] + (1.f - g) * (mund[idx] + acc);
}

extern "C" void kernel_launch(void* const* d_in, const int* in_sizes, int n_in,
                              void* d_out, int out_size, void* d_ws, size_t ws_size,
                              hipStream_t stream)
{
    (void)in_sizes; (void)n_in; (void)out_size; (void)ws_size;
    const float* c    = (const float*)d_in[0];
    const float* m    = (const float*)d_in[1];
    const float* k    = (const float*)d_in[2];
    const float* q    = (const float*)d_in[3];
    const float* cw   = (const float*)d_in[4];
    const int*   mask = (const int*)  d_in[5];
    const float* cs   = (const float*)d_in[6];
    const float* ms   = (const float*)d_in[7];
    const float* Wcq  = (const float*)d_in[8];
    const float* bcq  = (const float*)d_in[9];
    const float* Wca  = (const float*)d_in[10];
    const float* bca  = (const float*)d_in[11];
    const float* Wm_r = (const float*)d_in[12];
    const float* bm_r = (const float*)d_in[13];
    const float* Wk   = (const float*)d_in[14];
    const float* bk   = (const float*)d_in[15];
    const float* WI   = (const float*)d_in[16];
    const float* bI   = (const float*)d_in[17];
    const float* Wra  = (const float*)d_in[18];
    const float* bra  = (const float*)d_in[19];
    const float* Wm_w = (const float*)d_in[20];
    const float* bm_w = (const float*)d_in[21];
    const float* Wsa  = (const float*)d_in[22];
    const float* bsa  = (const float*)d_in[23];
    const float* Wm2  = (const float*)d_in[24];
    const float* bm2  = (const float*)d_in[25];
    const float* Wc   = (const float*)d_in[26];
    const float* bc   = (const float*)d_in[27];
    const float* Ws   = (const float*)d_in[28];

    float* out_cnew = (float*)d_out;
    float* out_mnew = out_cnew + BB*DD;
    float* out_cv   = out_mnew + BB*DD;
    float* out_rv   = out_cv + BB*LL;     // 25,690,112 f32 = 102,760,448 B

    // d_out rv region doubles as packed bf16 scratch for Ip / I2p (dead before rv write)
    char* Ip  = (char*)out_rv;                       // 256*16*12544 = 51,380,224 B
    char* I2p = (char*)out_rv + 51380224;            // 51,380,224 B

    char* w = (char*)d_ws;                 // total footprint: 55,575,552 B
    float* s0      = (float*)(w + 0);        // cq -> r (r zeroed by S1, atomics in S2)
    float* s1      = (float*)(w + 524288);   // cnew (alive until samsa)
    // pm_part overlays s2+s3 head (mI dead after conv1; mprev/msa written after S2)
    unsigned short* pm_part = (unsigned short*)(w + 1048576);  // 8*256*196*2 = 802,816 B
    // ps_part overlays the weight region (Wkb/WIb/Wrab dead after conv3)
    float* ps_part = (float*)(w + 2097152);                    // 8*256*196*4 = 1,605,632 B
    unsigned short* Wkb  = (unsigned short*)(w + 2097152);   // 512x512 bf16
    unsigned short* WIb  = (unsigned short*)(w + 2621440);   // 512x1024 bf16
    unsigned short* Wrab = (unsigned short*)(w + 3670016);   // 512x512 bf16
    char* kp_ra = (char*)(w + 4194304);      // kp (packed k); ra overwrites after conv2
    float* gate_w  = (float*)(w + 55574528); // 1024 B

    float* cq_w   = s0;
    float* r_w    = s0;
    float* cnew_w = s1;
    float* mI_w   = (float*)(w + 1048576);   // s2 region (dead before pm_part is written)
    float* mund_w = (float*)(w + 1048576);
    float* mprev_w= (float*)(w + 1572864);   // s3 region
    float* msa_w  = (float*)(w + 1572864);
    unsigned short* ra_w = (unsigned short*)kp_ra;   // conv3 output, [b][c][hw] bf16

    // Weight converts (f32 -> bf16), one launch
    cvt3_kernel<<<1024, 256, 0, stream>>>(Wk, Wkb, WI, WIb, Wra, Wrab);

    // Pack k once into (swizzled) MFMA-B layout (f32 103MB -> packed bf16 51MB)
    pack_x_kernel<<<dim3(BB, 16), 256, 0, stream>>>(k, kp_ra);

    // ControlUnit
    small_gemm_kernel<<<dim3(BB,2), 256, 0, stream>>>(c, DD, q, DD, Wcq, bcq, cq_w, DD);
    small_gemm_kernel<<<dim3(BB,2), 256, 0, stream>>>(m, DD, nullptr, 0, Wm_r, bm_r, mI_w, DD);
    control_kernel<<<BB, 256, 0, stream>>>(cq_w, cw, Wca, bca, mask, cnew_w, out_cv, out_cnew);

    // ReadUnit (MFMA convs): I = mI.(Wk k + bk); I2' = (WI [I;k] + bI).cnew; ra = Wra I2' + bra
    conv_mfma_kernel<<<dim3(BB, 4), 512, 0, stream>>>(kp_ra, 16, nullptr, 0,  Wkb,  DD,   bk,  mI_w,   Ip,   1);
    conv_mfma_kernel<<<dim3(BB, 4), 512, 0, stream>>>(Ip,    16, kp_ra,  16,  WIb,  2*DD, bI,  cnew_w, I2p,  1);
    conv_mfma_kernel<<<dim3(BB, 4), 512, 0, stream>>>(I2p,   16, nullptr, 0,  Wrab, DD,   bra, nullptr, ra_w, 0);

    // channel softmax + r, two-stage
    softmax_part_kernel<<<dim3(BB, 4), 512, 0, stream>>>((const bf16*)ra_w, pm_part, ps_part, r_w);
    softmax_rv_kernel<<<dim3(BB, 2), 512, 0, stream>>>((const bf16*)ra_w, k, pm_part, ps_part, out_rv, r_w);

    // WriteUnit
    small_gemm_kernel<<<dim3(BB,2), 256, 0, stream>>>(r_w, DD, m, DD, Wm_w, bm_w, mprev_w, DD);
    small_gemm_kernel<<<dim3(BB,2), 256, 0, stream>>>(mprev_w, DD, nullptr, 0, Wm2, bm2, mund_w, DD);
    samsa_kernel<<<BB, 256, 0, stream>>>(cs, ms, Wsa, bsa, cnew_w, Wc, bc, gate_w, msa_w);
    write_final_kernel<<<dim3(BB,2), 256, 0, stream>>>(msa_w, Ws, m, gate_w, mund_w, out_mnew);
}